// Round 11
// baseline (109.596 us; speedup 1.0000x reference)
//
#include <hip/hip_runtime.h>
#include <math.h>

#define NB 16
#define NN 1024
#define ND 128
#define NH 8
#define DH 16

typedef float f32x4 __attribute__((ext_vector_type(4)));
typedef short s16x4 __attribute__((ext_vector_type(4)));

static __device__ __forceinline__ ushort f2bf(float x) {
  unsigned u = __float_as_uint(x);
  u = (u + 0x7FFFu + ((u >> 16) & 1u)) >> 16;
  return (ushort)u;
}

// hardware 2^x (v_exp_f32); builtin so the hazard recognizer tracks it
static __device__ __forceinline__ float exp2h(float x) {
  return __builtin_amdgcn_exp2f(x);
}

// gelu via tanh form (max |err| vs exact erf ~5e-4; inputs here are |x|<~1)
static __device__ __forceinline__ float gelu_f(float x) {
  float u = 0.7978845608028654f * (x + 0.044715f * x * x * x);
  float au = fabsf(u);
  float tex = exp2h(-2.8853900817779268f * au);  // exp(-2|u|)
  float th = (1.0f - tex) / (1.0f + tex);
  th = copysignf(th, u);
  return 0.5f * x * (1.0f + th);
}

// D[a][b] = sum_k X[a][k]*Y[b][k] + C.  X/Y frag: lane l holds row (l&15),
// k = 4*(l>>4)..+3.  D: lane l holds rows 4*(l>>4)+j (j=0..3), col l&15.
static __device__ __forceinline__ f32x4 mfma16(s16x4 a, s16x4 b, f32x4 c) {
  return __builtin_amdgcn_mfma_f32_16x16x16bf16_1k(a, b, c, 0, 0, 0);
}

// pack 4 f32 -> 4 bf16. NO inline asm (R4/R8: asm defs invisible to MFMA
// hazard recognizer -> NaN).
static __device__ __forceinline__ s16x4 pack_bf4(float p0, float p1, float p2,
                                                 float p3) {
  s16x4 r = {(short)f2bf(p0), (short)f2bf(p1), (short)f2bf(p2),
             (short)f2bf(p3)};
  return r;
}

#define QSCALE 0.36067376022224085f  // log2(e)/4, folded into Q at store

// ---------- Kernel W: one-time weight conversion to bf16 ----------
__global__ __launch_bounds__(256) void kW(
    const float* __restrict__ eW, const float* __restrict__ qkvW,
    const float* __restrict__ outW, const float* __restrict__ W1,
    const float* __restrict__ W2, ushort* __restrict__ wbf) {
  int i = blockIdx.x * 256 + threadIdx.x;
  if (i < 18432) {
    int r = i / 144, k = i - r * 144;
    wbf[i] = (k < 129) ? f2bf(eW[r * 129 + k]) : (ushort)0;
  } else if (i < 67584) {
    wbf[i] = f2bf(qkvW[i - 18432]);
  } else if (i < 83968) {
    wbf[i] = f2bf(outW[i - 67584]);
  } else if (i < 100352) {
    wbf[i] = f2bf(W1[i - 83968]);
  } else if (i < 116736) {
    wbf[i] = f2bf(W2[i - 100352]);
  }
}

// ---------- Kernel A: sine-enc + eig linear + LN1 + QKV, 16 rows/block ----
// grid 1024 -> 4 blocks/CU (was 2): occupancy-bound fix.
__global__ __launch_bounds__(256, 6) void kA(
    const float* __restrict__ eva, const ushort* __restrict__ eWbf,
    const float* __restrict__ eb, const float* __restrict__ g1s,
    const float* __restrict__ g1b, const ushort* __restrict__ qkvbf,
    const float* __restrict__ qb, float* __restrict__ eig,
    ushort* __restrict__ qg, ushort* __restrict__ kg,
    ushort* __restrict__ vt) {
  __shared__ __align__(16) ushort ee[16][148];
  __shared__ __align__(16) float eig_f[16][132];
  __shared__ __align__(16) ushort hbf[16][132];
  int t = threadIdx.x;
  int rows0 = blockIdx.x * 16;
  int w = t >> 6, l = t & 63, g = l >> 4, c = l & 15;

  // phase 1: ee = [eva, sin(pe), cos(pe)] bf16
  {
    int d = t & 63, r0 = t >> 6;
    float div = __expf((float)(2 * d) * (-9.210340371976184f / 128.0f));
#pragma unroll
    for (int k = 0; k < 4; ++k) {
      int row = r0 + 4 * k;
      float e = eva[rows0 + row];
      float pe = e * 100.0f * div;
      ee[row][1 + d] = f2bf(__sinf(pe));
      ee[row][65 + d] = f2bf(__cosf(pe));
      if (d == 0) ee[row][0] = f2bf(e);
    }
  }
  for (int i = t; i < 16 * 19; i += 256) {
    int row = i / 19, cc = 129 + (i - row * 19);
    ee[row][cc] = 0;
  }
  __syncthreads();

  // phase 2: eig = ee @ eW^T + eb (K = 144); wave w -> col-tiles 2w, 2w+1
#pragma unroll
  for (int i = 0; i < 2; ++i) {
    int ct = w * 2 + i;
    f32x4 st = {0.f, 0.f, 0.f, 0.f};
#pragma unroll
    for (int kk = 0; kk < 9; ++kk) {
      s16x4 xf = *(const s16x4*)&ee[c][kk * 16 + g * 4];
      s16x4 yf = *(const s16x4*)&eWbf[(ct * 16 + c) * 144 + kk * 16 + g * 4];
      st = mfma16(xf, yf, st);
    }
    float bias = eb[ct * 16 + c];
#pragma unroll
    for (int j = 0; j < 4; ++j)
      eig_f[g * 4 + j][ct * 16 + c] = st[j] + bias;
  }
  __syncthreads();

  // eig residual out (f32, coalesced)
#pragma unroll
  for (int p = 0; p < 2; ++p) {
    int idx = p * 256 + t;
    int row = idx >> 5, c4 = idx & 31;
    *(float4*)&eig[(size_t)(rows0 + row) * ND + c4 * 4] =
        *(const float4*)&eig_f[row][c4 * 4];
  }

  // LN1 (16 lanes/row, stride-16 interleave)
  {
    int row = t >> 4, s = t & 15;
    float vals[8];
    float sum = 0.f;
#pragma unroll
    for (int k = 0; k < 8; ++k) {
      vals[k] = eig_f[row][s + 16 * k];
      sum += vals[k];
    }
    sum += __shfl_xor(sum, 1, 16);
    sum += __shfl_xor(sum, 2, 16);
    sum += __shfl_xor(sum, 4, 16);
    sum += __shfl_xor(sum, 8, 16);
    float mean = sum * (1.0f / 128.0f);
    float sq = 0.f;
#pragma unroll
    for (int k = 0; k < 8; ++k) {
      float d = vals[k] - mean;
      sq += d * d;
    }
    sq += __shfl_xor(sq, 1, 16);
    sq += __shfl_xor(sq, 2, 16);
    sq += __shfl_xor(sq, 4, 16);
    sq += __shfl_xor(sq, 8, 16);
    float rstd = rsqrtf(sq * (1.0f / 128.0f) + 1e-5f);
#pragma unroll
    for (int k = 0; k < 8; ++k) {
      int col = s + 16 * k;
      hbf[row][col] = f2bf((vals[k] - mean) * rstd * g1s[col] + g1b[col]);
    }
  }
  __syncthreads();

  // phase 3: QKV = h @ qkvW^T + qb; wave w -> col-tiles w*6..w*6+5
  {
    int b = rows0 >> 10, nn0 = rows0 & 1023;
#pragma unroll
    for (int i = 0; i < 6; ++i) {
      int ct = w * 6 + i;
      f32x4 st = {0.f, 0.f, 0.f, 0.f};
#pragma unroll
      for (int kk = 0; kk < 8; ++kk) {
        s16x4 xf = *(const s16x4*)&hbf[c][kk * 16 + g * 4];
        s16x4 yf = *(const s16x4*)&qkvbf[(ct * 16 + c) * 128 + kk * 16 + g * 4];
        st = mfma16(xf, yf, st);
      }
      float bias = qb[ct * 16 + c];
      int which = ct >> 3, head = ct & 7;
      if (which == 2) {
        unsigned lo = (unsigned)f2bf(st[0] + bias) |
                      ((unsigned)f2bf(st[1] + bias) << 16);
        unsigned hi = (unsigned)f2bf(st[2] + bias) |
                      ((unsigned)f2bf(st[3] + bias) << 16);
        uint2 pk;
        pk.x = lo;
        pk.y = hi;
        *(uint2*)(vt + ((size_t)(b * NH + head) * DH + c) * NN + nn0 + g * 4) =
            pk;
      } else {
        ushort* dst = which == 0 ? qg : kg;
        float sc = which == 0 ? QSCALE : 1.0f;
        size_t base = ((size_t)(b * NH + head) * NN + nn0 + g * 4) * DH + c;
#pragma unroll
        for (int j = 0; j < 4; ++j)
          dst[base + j * DH] = f2bf((st[j] + bias) * sc);
      }
    }
  }
}

// ---------- Kernel C: MFMA attention (R10, measured-neutral vs R9; kept) ----
__global__ __launch_bounds__(512) void k_attn(
    const ushort* __restrict__ qg, const ushort* __restrict__ kg,
    const ushort* __restrict__ vt, const int* __restrict__ length,
    ushort* __restrict__ att) {
  __shared__ ushort Ksh[2][128][20];
  __shared__ ushort VTsh[2][16][136];
  int bid = blockIdx.x;
  int bh = bid >> 3, qc = bid & 7;
  int b = bh >> 3, h = bh & 7;
  int t = threadIdx.x;
  int w = t >> 6, l = t & 63, g = l >> 4, c = l & 15;
  int len = length[b];
  int nt = (len + 127) >> 7;
  int qrow = qc * 128 + w * 16 + c;
  s16x4 qf = *(const s16x4*)(qg + ((size_t)bh * NN + qrow) * DH + g * 4);
  f32x4 oacc0 = {0.f, 0.f, 0.f, 0.f};
  f32x4 oacc1 = {0.f, 0.f, 0.f, 0.f};
  float lsum = 0.f;
  int ksr = t >> 2, ksc = t & 3;
  int vr = t >> 5, vc = t & 31;
  const ushort* kbg = kg + (size_t)bh * NN * DH;
  const ushort* vbg = vt + (size_t)bh * DH * NN;

  {
    uint2 kv = *(const uint2*)(kbg + (size_t)ksr * DH + ksc * 4);
    uint2 vv = *(const uint2*)(vbg + (size_t)vr * NN + vc * 4);
    *(uint2*)&Ksh[0][ksr][ksc * 4] = kv;
    *(uint2*)&VTsh[0][vr][vc * 4] = vv;
  }
  __syncthreads();

  int cur = 0;
  for (int ti = 0; ti < nt; ++ti) {
    int t0 = ti << 7;
    bool pre = (ti + 1 < nt);
    uint2 kvn = {0u, 0u}, vvn = {0u, 0u};
    if (pre) {
      int t1 = t0 + 128;
      kvn = *(const uint2*)(kbg + (size_t)(t1 + ksr) * DH + ksc * 4);
      vvn = *(const uint2*)(vbg + (size_t)vr * NN + t1 + vc * 4);
    }
    if (t0 + 128 <= len) {
      __builtin_amdgcn_s_setprio(1);
#pragma unroll
      for (int kt = 0; kt < 8; ++kt) {
        s16x4 kf = *(const s16x4*)&Ksh[cur][kt * 16 + c][g * 4];
        f32x4 st = {0.f, 0.f, 0.f, 0.f};
        st = mfma16(kf, qf, st);
        float p0 = exp2h(st[0]), p1 = exp2h(st[1]);
        float p2 = exp2h(st[2]), p3 = exp2h(st[3]);
        lsum += (p0 + p1) + (p2 + p3);
        s16x4 pf = pack_bf4(p0, p1, p2, p3);
        s16x4 vf = *(const s16x4*)&VTsh[cur][c][kt * 16 + g * 4];
        if (kt & 1) oacc1 = mfma16(vf, pf, oacc1);
        else oacc0 = mfma16(vf, pf, oacc0);
      }
      __builtin_amdgcn_s_setprio(0);
    } else {
      for (int kt = 0; kt < 8 && t0 + kt * 16 < len; ++kt) {
        s16x4 kf = *(const s16x4*)&Ksh[cur][kt * 16 + c][g * 4];
        f32x4 st = {0.f, 0.f, 0.f, 0.f};
        st = mfma16(kf, qf, st);
        int kj = t0 + kt * 16 + g * 4;
        float p0 = (kj + 0 < len) ? exp2h(st[0]) : 0.f;
        float p1 = (kj + 1 < len) ? exp2h(st[1]) : 0.f;
        float p2 = (kj + 2 < len) ? exp2h(st[2]) : 0.f;
        float p3 = (kj + 3 < len) ? exp2h(st[3]) : 0.f;
        lsum += (p0 + p1) + (p2 + p3);
        s16x4 pf = pack_bf4(p0, p1, p2, p3);
        s16x4 vf = *(const s16x4*)&VTsh[cur][c][kt * 16 + g * 4];
        if (kt & 1) oacc1 = mfma16(vf, pf, oacc1);
        else oacc0 = mfma16(vf, pf, oacc0);
      }
    }
    if (pre) {
      *(uint2*)&Ksh[cur ^ 1][ksr][ksc * 4] = kvn;
      *(uint2*)&VTsh[cur ^ 1][vr][vc * 4] = vvn;
      __syncthreads();
      cur ^= 1;
    }
  }
  f32x4 oacc = {oacc0[0] + oacc1[0], oacc0[1] + oacc1[1],
                oacc0[2] + oacc1[2], oacc0[3] + oacc1[3]};
  lsum += __shfl_xor(lsum, 16, 64);
  lsum += __shfl_xor(lsum, 32, 64);
  float inv = 1.0f / lsum;
  s16x4 ob = pack_bf4(oacc[0] * inv, oacc[1] * inv, oacc[2] * inv,
                      oacc[3] * inv);
  *(s16x4*)(att + ((size_t)b * NN + qrow) * ND + h * DH + g * 4) = ob;
}

// ---------- Kernel B: outproj + residual + LN2 + FFN + colsum, 16 rows ----
__global__ __launch_bounds__(256, 6) void kB(
    const ushort* __restrict__ attg, const ushort* __restrict__ outbf,
    const float* __restrict__ ob, const float* __restrict__ g2s,
    const float* __restrict__ g2b, const ushort* __restrict__ w1bf,
    const float* __restrict__ fb1, const ushort* __restrict__ w2bf,
    const float* __restrict__ fb2, const float* __restrict__ eig,
    const int* __restrict__ length, float* __restrict__ bsum) {
  __shared__ __align__(16) ushort attb[16][136];
  __shared__ __align__(16) float eig_f[16][132];
  __shared__ __align__(16) ushort hbf[16][132];
  __shared__ float csum[2][128];
  int t = threadIdx.x;
  int rows0 = blockIdx.x * 16;
  int w = t >> 6, l = t & 63, g = l >> 4, c = l & 15;

  {
    int row = t >> 4, c8 = t & 15;
    *(uint4*)&attb[row][c8 * 8] =
        *(const uint4*)&attg[(size_t)(rows0 + row) * ND + c8 * 8];
  }
#pragma unroll
  for (int p = 0; p < 2; ++p) {
    int idx = p * 256 + t;
    int row = idx >> 5, c4 = idx & 31;
    *(float4*)&eig_f[row][c4 * 4] =
        *(const float4*)&eig[(size_t)(rows0 + row) * ND + c4 * 4];
  }
  __syncthreads();

  // outproj + residual
#pragma unroll
  for (int i = 0; i < 2; ++i) {
    int ct = w * 2 + i;
    f32x4 st = {0.f, 0.f, 0.f, 0.f};
#pragma unroll
    for (int kk = 0; kk < 8; ++kk) {
      s16x4 xf = *(const s16x4*)&attb[c][kk * 16 + g * 4];
      s16x4 yf = *(const s16x4*)&outbf[(ct * 16 + c) * 128 + kk * 16 + g * 4];
      st = mfma16(xf, yf, st);
    }
    float bias = ob[ct * 16 + c];
#pragma unroll
    for (int j = 0; j < 4; ++j) {
      int row = g * 4 + j, col = ct * 16 + c;
      eig_f[row][col] = st[j] + bias + eig_f[row][col];
    }
  }
  __syncthreads();

  // LN2 (16 lanes/row)
  {
    int row = t >> 4, s = t & 15;
    float vals[8];
    float sum = 0.f;
#pragma unroll
    for (int k = 0; k < 8; ++k) {
      vals[k] = eig_f[row][s + 16 * k];
      sum += vals[k];
    }
    sum += __shfl_xor(sum, 1, 16);
    sum += __shfl_xor(sum, 2, 16);
    sum += __shfl_xor(sum, 4, 16);
    sum += __shfl_xor(sum, 8, 16);
    float mean = sum * (1.0f / 128.0f);
    float sq = 0.f;
#pragma unroll
    for (int k = 0; k < 8; ++k) {
      float d = vals[k] - mean;
      sq += d * d;
    }
    sq += __shfl_xor(sq, 1, 16);
    sq += __shfl_xor(sq, 2, 16);
    sq += __shfl_xor(sq, 4, 16);
    sq += __shfl_xor(sq, 8, 16);
    float rstd = rsqrtf(sq * (1.0f / 128.0f) + 1e-5f);
#pragma unroll
    for (int k = 0; k < 8; ++k) {
      int col = s + 16 * k;
      hbf[row][col] = f2bf((vals[k] - mean) * rstd * g2s[col] + g2b[col]);
    }
  }
  __syncthreads();

  // FFN1 + gelu -> attb
#pragma unroll
  for (int i = 0; i < 2; ++i) {
    int ct = w * 2 + i;
    f32x4 st = {0.f, 0.f, 0.f, 0.f};
#pragma unroll
    for (int kk = 0; kk < 8; ++kk) {
      s16x4 xf = *(const s16x4*)&hbf[c][kk * 16 + g * 4];
      s16x4 yf = *(const s16x4*)&w1bf[(ct * 16 + c) * 128 + kk * 16 + g * 4];
      st = mfma16(xf, yf, st);
    }
    float bias = fb1[ct * 16 + c];
#pragma unroll
    for (int j = 0; j < 4; ++j)
      attb[g * 4 + j][ct * 16 + c] = f2bf(gelu_f(st[j] + bias));
  }
  __syncthreads();

  // FFN2 + residual
#pragma unroll
  for (int i = 0; i < 2; ++i) {
    int ct = w * 2 + i;
    f32x4 st = {0.f, 0.f, 0.f, 0.f};
#pragma unroll
    for (int kk = 0; kk < 8; ++kk) {
      s16x4 xf = *(const s16x4*)&attb[c][kk * 16 + g * 4];
      s16x4 yf = *(const s16x4*)&w2bf[(ct * 16 + c) * 128 + kk * 16 + g * 4];
      st = mfma16(xf, yf, st);
    }
    float bias = fb2[ct * 16 + c];
#pragma unroll
    for (int j = 0; j < 4; ++j) {
      int row = g * 4 + j, col = ct * 16 + c;
      eig_f[row][col] = st[j] + bias + eig_f[row][col];
    }
  }
  __syncthreads();

  // masked column-sum of final rows (pooling is linear)
  {
    int b = rows0 >> 10, n0 = rows0 & 1023;
    int len = length[b];
    int col = t & 127, half = t >> 7;
    float s = 0.f;
#pragma unroll
    for (int r = 0; r < 8; ++r) {
      int row = half * 8 + r;
      if (n0 + row < len) s += eig_f[row][col];
    }
    csum[half][col] = s;
  }
  __syncthreads();
  if (t < 128) bsum[(size_t)blockIdx.x * 128 + t] = csum[0][t] + csum[1][t];
}

// ---------- Kernel F: pooling head + Chebyshev synthesis + tight frame ----
// kE fused in: each block serves one batch (4 blocks/batch recompute coe).
__global__ __launch_bounds__(256) void k_wave(
    const float* __restrict__ eva, const float* __restrict__ bsum,
    const int* __restrict__ length, const float* __restrict__ dsW,
    const float* __restrict__ dsB, const float* __restrict__ dwW,
    const float* __restrict__ dwB, const float* __restrict__ dlW,
    const float* __restrict__ dlB, float* __restrict__ out) {
  __shared__ float s[128];
  __shared__ float pg[20];
  __shared__ float nrm[2];
  __shared__ float cb[20];
  int t = threadIdx.x;
  int b = blockIdx.x >> 2;  // 4 blocks per batch
  if (t < 128) {
    float a = 0.f;
#pragma unroll
    for (int c = 0; c < 64; ++c) a += bsum[(size_t)(b * 64 + c) * 128 + t];
    s[t] = a;
  }
  __syncthreads();
  if (t < 20) {
    const float* W = t < 8 ? dsW + t * 128
                           : (t < 16 ? dwW + (t - 8) * 128 : dlW + (t - 16) * 128);
    float bias = t < 8 ? dsB[t] : (t < 16 ? dwB[t - 8] : dlB[t - 16]);
    float d = 0.f;
    for (int j = 0; j < 128; ++j) d += s[j] * W[j];
    float lf = (float)length[b];
    float pooled = (d + lf * bias) / (lf + 1e-8f);
    pg[t] = 1.f / (1.f + expf(-pooled));
  }
  __syncthreads();
  if (t == 0) {
    float a1 = 0.f, a2 = 0.f;
    for (int i = 0; i < 8; ++i) a1 += pg[i];
    for (int i = 8; i < 16; ++i) a2 += pg[i];
    nrm[0] = a1 + 1e-8f;
    nrm[1] = a2 + 1e-8f;
  }
  __syncthreads();
  if (t < 8) cb[t] = pg[t] / nrm[0];
  else if (t < 16) cb[t] = pg[t] / nrm[1];
  else if (t < 20) cb[t] = pg[t] * 2.0f;
  __syncthreads();

  int bn = blockIdx.x * 256 + t;
  float e = eva[bn];
  float y = e - 1.0f;
  float te = 1.0f, to = y;
  float cs = cb[0] * 0.5f * (1.0f - to);
#pragma unroll
  for (int i = 1; i < 8; ++i) {
    te = 2.f * y * to - te;
    to = 2.f * y * te - to;
    cs += cb[i] * 0.5f * (1.0f - to);
  }
  float cw[4];
#pragma unroll
  for (int j = 0; j < 4; ++j) {
    float fs = e * cb[16 + j];
    fs = (fs > 2.0f) ? 0.0f : fs;
    float yw = fs - 1.0f;
    float te2 = 1.0f, to2 = yw;
    float acc = 0.0f;
#pragma unroll
    for (int i = 1; i < 8; ++i) {
      te2 = 2.f * yw * to2 - te2;
      to2 = 2.f * yw * te2 - to2;
      acc += cb[8 + i] * 0.5f * (1.0f - te2);
    }
    cw[j] = acc;
  }
  float nr = cs * cs + cw[0] * cw[0] + cw[1] * cw[1] + cw[2] * cw[2] +
             cw[3] * cw[3];
  float inv = 1.0f / (sqrtf(nr) + 1e-8f);
  float* o = out + bn * 5;
  o[0] = cs * inv;
  o[1] = cw[0] * inv;
  o[2] = cw[1] * inv;
  o[3] = cw[2] * inv;
  o[4] = cw[3] * inv;
}

extern "C" void kernel_launch(void* const* d_in, const int* in_sizes, int n_in,
                              void* d_out, int out_size, void* d_ws,
                              size_t ws_size, hipStream_t stream) {
  const float* eva = (const float*)d_in[1];
  const int* length = (const int*)d_in[2];
  const float* eig_w_W = (const float*)d_in[3];
  const float* eig_w_b = (const float*)d_in[4];
  const float* ln1_s = (const float*)d_in[5];
  const float* ln1_b = (const float*)d_in[6];
  const float* ln2_s = (const float*)d_in[7];
  const float* ln2_b = (const float*)d_in[8];
  const float* qkv_W = (const float*)d_in[9];
  const float* qkv_b = (const float*)d_in[10];
  const float* out_W = (const float*)d_in[11];
  const float* out_b = (const float*)d_in[12];
  const float* ffn_W1 = (const float*)d_in[13];
  const float* ffn_b1 = (const float*)d_in[14];
  const float* ffn_W2 = (const float*)d_in[15];
  const float* ffn_b2 = (const float*)d_in[16];
  const float* dec_sca_W = (const float*)d_in[17];
  const float* dec_sca_b = (const float*)d_in[18];
  const float* dec_wav_W = (const float*)d_in[19];
  const float* dec_wav_b = (const float*)d_in[20];
  const float* dec_scl_W = (const float*)d_in[21];
  const float* dec_scl_b = (const float*)d_in[22];

  float* ws = (float*)d_ws;
  const size_t SZ = (size_t)NB * NN * ND;  // 2097152
  float* eig = ws;                         // f32 [16384][128]
  ushort* qg = (ushort*)(ws + SZ);         // bf16 [b,h,n,16] (scaled)
  ushort* kg = qg + SZ;                    // bf16 [b,h,n,16]
  ushort* vt = kg + SZ;                    // bf16 [b,h,d,n]
  ushort* attg = vt + SZ;                  // bf16 [16384][128]
  float* bsum = (float*)(attg + SZ);       // f32 [1024][128]
  ushort* wbf = (ushort*)(bsum + 1024 * 128);  // bf16 weights
  ushort* eWbf = wbf;
  ushort* qkvbf = wbf + 18432;
  ushort* outbf = wbf + 67584;
  ushort* w1bf = wbf + 83968;
  ushort* w2bf = wbf + 100352;

  kW<<<(116736 + 255) / 256, 256, 0, stream>>>(eig_w_W, qkv_W, out_W, ffn_W1,
                                               ffn_W2, wbf);
  kA<<<NB * NN / 16, 256, 0, stream>>>(eva, eWbf, eig_w_b, ln1_s, ln1_b, qkvbf,
                                       qkv_b, eig, qg, kg, vt);
  k_attn<<<NB * NH * 8, 512, 0, stream>>>(qg, kg, vt, length, attg);
  kB<<<NB * NN / 16, 256, 0, stream>>>(attg, outbf, out_b, ln2_s, ln2_b, w1bf,
                                       ffn_b1, w2bf, ffn_b2, eig, length, bsum);
  k_wave<<<(NB * NN) / 256, 256, 0, stream>>>(eva, bsum, length, dec_sca_W,
                                              dec_sca_b, dec_wav_W, dec_wav_b,
                                              dec_scl_W, dec_scl_b,
                                              (float*)d_out);
}

// Round 12
// 97.980 us; speedup vs baseline: 1.1186x; 1.1186x over previous
//
#include <hip/hip_runtime.h>
#include <math.h>

#define NB 16
#define NN 1024
#define ND 128
#define NH 8
#define DH 16

typedef float f32x4 __attribute__((ext_vector_type(4)));
typedef short s16x4 __attribute__((ext_vector_type(4)));

static __device__ __forceinline__ ushort f2bf(float x) {
  unsigned u = __float_as_uint(x);
  u = (u + 0x7FFFu + ((u >> 16) & 1u)) >> 16;
  return (ushort)u;
}

// hardware 2^x (v_exp_f32); builtin so the hazard recognizer tracks it
static __device__ __forceinline__ float exp2h(float x) {
  return __builtin_amdgcn_exp2f(x);
}

// D[a][b] = sum_k X[a][k]*Y[b][k] + C.  X/Y frag: lane l holds row (l&15),
// k = 4*(l>>4)..+3.  D: lane l holds rows 4*(l>>4)+j (j=0..3), col l&15.
static __device__ __forceinline__ f32x4 mfma16(s16x4 a, s16x4 b, f32x4 c) {
  return __builtin_amdgcn_mfma_f32_16x16x16bf16_1k(a, b, c, 0, 0, 0);
}

// pack 4 f32 -> 4 bf16. NO inline asm (R4/R8: asm defs invisible to MFMA
// hazard recognizer -> NaN).
static __device__ __forceinline__ s16x4 pack_bf4(float p0, float p1, float p2,
                                                 float p3) {
  s16x4 r = {(short)f2bf(p0), (short)f2bf(p1), (short)f2bf(p2),
             (short)f2bf(p3)};
  return r;
}

#define QSCALE 0.36067376022224085f  // log2(e)/4, folded into Q at store

// ---------- Kernel W: one-time weight conversion to bf16 ----------
__global__ __launch_bounds__(256) void kW(
    const float* __restrict__ eW, const float* __restrict__ qkvW,
    const float* __restrict__ outW, const float* __restrict__ W1,
    const float* __restrict__ W2, ushort* __restrict__ wbf) {
  int i = blockIdx.x * 256 + threadIdx.x;
  if (i < 18432) {
    int r = i / 144, k = i - r * 144;
    wbf[i] = (k < 129) ? f2bf(eW[r * 129 + k]) : (ushort)0;
  } else if (i < 67584) {
    wbf[i] = f2bf(qkvW[i - 18432]);
  } else if (i < 83968) {
    wbf[i] = f2bf(outW[i - 67584]);
  } else if (i < 100352) {
    wbf[i] = f2bf(W1[i - 83968]);
  } else if (i < 116736) {
    wbf[i] = f2bf(W2[i - 100352]);
  }
}

// ---------- Kernel A: sine-enc + eig linear + LN1 + QKV, MFMA, 32 rows/block --
// (R9 state: 32 rows/block amortizes the per-block weight stream; R11's
// 16-row split doubled weight traffic and regressed.)
__global__ __launch_bounds__(256, 4) void kA(
    const float* __restrict__ eva, const ushort* __restrict__ eWbf,
    const float* __restrict__ eb, const float* __restrict__ g1s,
    const float* __restrict__ g1b, const ushort* __restrict__ qkvbf,
    const float* __restrict__ qb, float* __restrict__ eig,
    ushort* __restrict__ qg, ushort* __restrict__ kg,
    ushort* __restrict__ vt) {
  __shared__ __align__(16) ushort ee[32][148];
  __shared__ __align__(16) float eig_f[32][132];
  __shared__ __align__(16) ushort hbf[32][132];
  int t = threadIdx.x;
  int rows0 = blockIdx.x * 32;
  int w = t >> 6, l = t & 63, g = l >> 4, c = l & 15;

  // phase 1: ee = [eva, sin(pe), cos(pe)] bf16; div loop-invariant per thread
  {
    int d = t & 63, r0 = t >> 6;
    float div = __expf((float)(2 * d) * (-9.210340371976184f / 128.0f));
#pragma unroll
    for (int k = 0; k < 8; ++k) {
      int row = r0 + 4 * k;
      float e = eva[rows0 + row];
      float pe = e * 100.0f * div;
      ee[row][1 + d] = f2bf(__sinf(pe));
      ee[row][65 + d] = f2bf(__cosf(pe));
      if (d == 0) ee[row][0] = f2bf(e);
    }
  }
  for (int i = t; i < 32 * 19; i += 256) {
    int row = i / 19, cc = 129 + (i - row * 19);
    ee[row][cc] = 0;
  }
  __syncthreads();

  // phase 2: eig = ee @ eW^T + eb (K = 144)
  {
    int rt = w >> 1;
#pragma unroll
    for (int i = 0; i < 4; ++i) {
      int ct = (w & 1) * 4 + i;
      f32x4 st = {0.f, 0.f, 0.f, 0.f};
#pragma unroll
      for (int kk = 0; kk < 9; ++kk) {
        s16x4 xf = *(const s16x4*)&ee[rt * 16 + c][kk * 16 + g * 4];
        s16x4 yf = *(const s16x4*)&eWbf[(ct * 16 + c) * 144 + kk * 16 + g * 4];
        st = mfma16(xf, yf, st);
      }
      float bias = eb[ct * 16 + c];
#pragma unroll
      for (int j = 0; j < 4; ++j)
        eig_f[rt * 16 + g * 4 + j][ct * 16 + c] = st[j] + bias;
    }
  }
  __syncthreads();

  // eig residual out (f32, coalesced)
#pragma unroll
  for (int p = 0; p < 4; ++p) {
    int idx = p * 256 + t;
    int row = idx >> 5, c4 = idx & 31;
    *(float4*)&eig[(size_t)(rows0 + row) * ND + c4 * 4] =
        *(const float4*)&eig_f[row][c4 * 4];
  }

  // LN1 (8 lanes/row, stride-8 interleave)
  {
    int row = t >> 3, s = t & 7;
    float vals[16];
    float sum = 0.f;
#pragma unroll
    for (int k = 0; k < 16; ++k) {
      vals[k] = eig_f[row][s + 8 * k];
      sum += vals[k];
    }
    sum += __shfl_xor(sum, 1, 8);
    sum += __shfl_xor(sum, 2, 8);
    sum += __shfl_xor(sum, 4, 8);
    float mean = sum * (1.0f / 128.0f);
    float sq = 0.f;
#pragma unroll
    for (int k = 0; k < 16; ++k) {
      float d = vals[k] - mean;
      sq += d * d;
    }
    sq += __shfl_xor(sq, 1, 8);
    sq += __shfl_xor(sq, 2, 8);
    sq += __shfl_xor(sq, 4, 8);
    float rstd = rsqrtf(sq * (1.0f / 128.0f) + 1e-5f);
#pragma unroll
    for (int k = 0; k < 16; ++k) {
      int col = s + 8 * k;
      hbf[row][col] = f2bf((vals[k] - mean) * rstd * g1s[col] + g1b[col]);
    }
  }
  __syncthreads();

  // phase 3: QKV = h @ qkvW^T + qb; q scaled; v stored transposed
  {
    int rt = w >> 1;
    int b = rows0 >> 10, nn0 = rows0 & 1023;
#pragma unroll
    for (int i = 0; i < 12; ++i) {
      int ct = (w & 1) * 12 + i;
      f32x4 st = {0.f, 0.f, 0.f, 0.f};
#pragma unroll
      for (int kk = 0; kk < 8; ++kk) {
        s16x4 xf = *(const s16x4*)&hbf[rt * 16 + c][kk * 16 + g * 4];
        s16x4 yf = *(const s16x4*)&qkvbf[(ct * 16 + c) * 128 + kk * 16 + g * 4];
        st = mfma16(xf, yf, st);
      }
      float bias = qb[ct * 16 + c];
      int which = ct >> 3, head = ct & 7;
      if (which == 2) {
        // vt[((b*8+head)*16 + d=c)*1024 + n], n = nn0+rt*16+g*4+j consecutive
        unsigned lo = (unsigned)f2bf(st[0] + bias) |
                      ((unsigned)f2bf(st[1] + bias) << 16);
        unsigned hi = (unsigned)f2bf(st[2] + bias) |
                      ((unsigned)f2bf(st[3] + bias) << 16);
        uint2 pk;
        pk.x = lo;
        pk.y = hi;
        *(uint2*)(vt + ((size_t)(b * NH + head) * DH + c) * NN + nn0 +
                  rt * 16 + g * 4) = pk;
      } else {
        ushort* dst = which == 0 ? qg : kg;
        float sc = which == 0 ? QSCALE : 1.0f;
        size_t base =
            ((size_t)(b * NH + head) * NN + nn0 + rt * 16 + g * 4) * DH + c;
#pragma unroll
        for (int j = 0; j < 4; ++j)
          dst[base + j * DH] = f2bf((st[j] + bias) * sc);
      }
    }
  }
}

// ---------- Kernel C: MFMA attention (R9 state) ----------
__global__ __launch_bounds__(512) void k_attn(
    const ushort* __restrict__ qg, const ushort* __restrict__ kg,
    const ushort* __restrict__ vt, const int* __restrict__ length,
    ushort* __restrict__ att) {
  __shared__ ushort Ksh[128][20];
  __shared__ ushort VTsh[16][136];
  int bid = blockIdx.x;
  int bh = bid >> 3, qc = bid & 7;
  int b = bh >> 3, h = bh & 7;
  int t = threadIdx.x;
  int w = t >> 6, l = t & 63, g = l >> 4, c = l & 15;
  int len = length[b];
  int qrow = qc * 128 + w * 16 + c;
  s16x4 qf = *(const s16x4*)(qg + ((size_t)bh * NN + qrow) * DH + g * 4);
  f32x4 oacc = {0.f, 0.f, 0.f, 0.f};
  float lsum = 0.f;
  int ksr = t >> 2, ksc = t & 3;
  int vr = t >> 5, vc = t & 31;
  const ushort* kbg = kg + (size_t)bh * NN * DH;
  const ushort* vbg = vt + (size_t)bh * DH * NN;
  for (int t0 = 0; t0 < len; t0 += 128) {
    *(uint2*)&Ksh[ksr][ksc * 4] =
        *(const uint2*)(kbg + (size_t)(t0 + ksr) * DH + ksc * 4);
    *(uint2*)&VTsh[vr][vc * 4] =
        *(const uint2*)(vbg + (size_t)vr * NN + t0 + vc * 4);
    __syncthreads();
    if (t0 + 128 <= len) {
#pragma unroll
      for (int kt = 0; kt < 8; ++kt) {
        s16x4 kf = *(const s16x4*)&Ksh[kt * 16 + c][g * 4];
        f32x4 st = {0.f, 0.f, 0.f, 0.f};
        st = mfma16(kf, qf, st);
        float p0 = exp2h(st[0]), p1 = exp2h(st[1]);
        float p2 = exp2h(st[2]), p3 = exp2h(st[3]);
        lsum += (p0 + p1) + (p2 + p3);
        s16x4 pf = pack_bf4(p0, p1, p2, p3);
        s16x4 vf = *(const s16x4*)&VTsh[c][kt * 16 + g * 4];
        oacc = mfma16(vf, pf, oacc);
      }
    } else {
      for (int kt = 0; kt < 8 && t0 + kt * 16 < len; ++kt) {
        s16x4 kf = *(const s16x4*)&Ksh[kt * 16 + c][g * 4];
        f32x4 st = {0.f, 0.f, 0.f, 0.f};
        st = mfma16(kf, qf, st);
        int kj = t0 + kt * 16 + g * 4;
        float p0 = (kj + 0 < len) ? exp2h(st[0]) : 0.f;
        float p1 = (kj + 1 < len) ? exp2h(st[1]) : 0.f;
        float p2 = (kj + 2 < len) ? exp2h(st[2]) : 0.f;
        float p3 = (kj + 3 < len) ? exp2h(st[3]) : 0.f;
        lsum += (p0 + p1) + (p2 + p3);
        s16x4 pf = pack_bf4(p0, p1, p2, p3);
        s16x4 vf = *(const s16x4*)&VTsh[c][kt * 16 + g * 4];
        oacc = mfma16(vf, pf, oacc);
      }
    }
    __syncthreads();
  }
  lsum += __shfl_xor(lsum, 16, 64);
  lsum += __shfl_xor(lsum, 32, 64);
  float inv = 1.0f / lsum;
  s16x4 ob = pack_bf4(oacc[0] * inv, oacc[1] * inv, oacc[2] * inv,
                      oacc[3] * inv);
  *(s16x4*)(att + ((size_t)b * NN + qrow) * ND + h * DH + g * 4) = ob;
}

// ---------- Kernel B: outproj + residual + LN2 + FFN + pooled colsum ----------
// (R9 state: 32 rows/block)
__global__ __launch_bounds__(256, 4) void kB(
    const ushort* __restrict__ attg, const ushort* __restrict__ outbf,
    const float* __restrict__ ob, const float* __restrict__ g2s,
    const float* __restrict__ g2b, const ushort* __restrict__ w1bf,
    const float* __restrict__ fb1, const ushort* __restrict__ w2bf,
    const float* __restrict__ fb2, const float* __restrict__ eig,
    const int* __restrict__ length, float* __restrict__ bsum) {
  __shared__ __align__(16) ushort attb[32][136];
  __shared__ __align__(16) float eig_f[32][132];
  __shared__ __align__(16) ushort hbf[32][132];
  __shared__ float csum[2][128];
  int t = threadIdx.x;
  int rows0 = blockIdx.x * 32;
  int w = t >> 6, l = t & 63, g = l >> 4, c = l & 15;
  int rt = w >> 1;

#pragma unroll
  for (int p = 0; p < 2; ++p) {
    int idx = p * 256 + t;
    int row = idx >> 4, c8 = idx & 15;
    *(uint4*)&attb[row][c8 * 8] =
        *(const uint4*)&attg[(size_t)(rows0 + row) * ND + c8 * 8];
  }
#pragma unroll
  for (int p = 0; p < 4; ++p) {
    int idx = p * 256 + t;
    int row = idx >> 5, c4 = idx & 31;
    *(float4*)&eig_f[row][c4 * 4] =
        *(const float4*)&eig[(size_t)(rows0 + row) * ND + c4 * 4];
  }
  __syncthreads();

  // outproj + residual
#pragma unroll
  for (int i = 0; i < 4; ++i) {
    int ct = (w & 1) * 4 + i;
    f32x4 st = {0.f, 0.f, 0.f, 0.f};
#pragma unroll
    for (int kk = 0; kk < 8; ++kk) {
      s16x4 xf = *(const s16x4*)&attb[rt * 16 + c][kk * 16 + g * 4];
      s16x4 yf = *(const s16x4*)&outbf[(ct * 16 + c) * 128 + kk * 16 + g * 4];
      st = mfma16(xf, yf, st);
    }
    float bias = ob[ct * 16 + c];
#pragma unroll
    for (int j = 0; j < 4; ++j) {
      int row = rt * 16 + g * 4 + j, col = ct * 16 + c;
      eig_f[row][col] = st[j] + bias + eig_f[row][col];
    }
  }
  __syncthreads();

  // LN2
  {
    int row = t >> 3, s = t & 7;
    float vals[16];
    float sum = 0.f;
#pragma unroll
    for (int k = 0; k < 16; ++k) {
      vals[k] = eig_f[row][s + 8 * k];
      sum += vals[k];
    }
    sum += __shfl_xor(sum, 1, 8);
    sum += __shfl_xor(sum, 2, 8);
    sum += __shfl_xor(sum, 4, 8);
    float mean = sum * (1.0f / 128.0f);
    float sq = 0.f;
#pragma unroll
    for (int k = 0; k < 16; ++k) {
      float d = vals[k] - mean;
      sq += d * d;
    }
    sq += __shfl_xor(sq, 1, 8);
    sq += __shfl_xor(sq, 2, 8);
    sq += __shfl_xor(sq, 4, 8);
    float rstd = rsqrtf(sq * (1.0f / 128.0f) + 1e-5f);
#pragma unroll
    for (int k = 0; k < 16; ++k) {
      int col = s + 8 * k;
      hbf[row][col] = f2bf((vals[k] - mean) * rstd * g2s[col] + g2b[col]);
    }
  }
  __syncthreads();

  // FFN1 + exact gelu -> attb
#pragma unroll
  for (int i = 0; i < 4; ++i) {
    int ct = (w & 1) * 4 + i;
    f32x4 st = {0.f, 0.f, 0.f, 0.f};
#pragma unroll
    for (int kk = 0; kk < 8; ++kk) {
      s16x4 xf = *(const s16x4*)&hbf[rt * 16 + c][kk * 16 + g * 4];
      s16x4 yf = *(const s16x4*)&w1bf[(ct * 16 + c) * 128 + kk * 16 + g * 4];
      st = mfma16(xf, yf, st);
    }
    float bias = fb1[ct * 16 + c];
#pragma unroll
    for (int j = 0; j < 4; ++j) {
      float gv = st[j] + bias;
      attb[rt * 16 + g * 4 + j][ct * 16 + c] =
          f2bf(0.5f * gv * (1.0f + erff(gv * 0.7071067811865475f)));
    }
  }
  __syncthreads();

  // FFN2 + residual
#pragma unroll
  for (int i = 0; i < 4; ++i) {
    int ct = (w & 1) * 4 + i;
    f32x4 st = {0.f, 0.f, 0.f, 0.f};
#pragma unroll
    for (int kk = 0; kk < 8; ++kk) {
      s16x4 xf = *(const s16x4*)&attb[rt * 16 + c][kk * 16 + g * 4];
      s16x4 yf = *(const s16x4*)&w2bf[(ct * 16 + c) * 128 + kk * 16 + g * 4];
      st = mfma16(xf, yf, st);
    }
    float bias = fb2[ct * 16 + c];
#pragma unroll
    for (int j = 0; j < 4; ++j) {
      int row = rt * 16 + g * 4 + j, col = ct * 16 + c;
      eig_f[row][col] = st[j] + bias + eig_f[row][col];
    }
  }
  __syncthreads();

  // masked column-sum of final eig rows (pooling is linear)
  {
    int b = rows0 >> 10, n0 = rows0 & 1023;
    int len = length[b];
    int col = t & 127, half = t >> 7;
    float s = 0.f;
#pragma unroll
    for (int r = 0; r < 16; ++r) {
      int row = half * 16 + r;
      if (n0 + row < len) s += eig_f[row][col];
    }
    csum[half][col] = s;
  }
  __syncthreads();
  if (t < 128) bsum[(size_t)blockIdx.x * 128 + t] = csum[0][t] + csum[1][t];
}

// ---------- Kernel F: pooling head + Chebyshev synthesis + tight frame ----
// kE fused: each block recomputes its batch's 20 coefficients from bsum
// (32 chunks/batch), then synthesizes 256 rows. One fewer launch than R9.
__global__ __launch_bounds__(256) void k_wave(
    const float* __restrict__ eva, const float* __restrict__ bsum,
    const int* __restrict__ length, const float* __restrict__ dsW,
    const float* __restrict__ dsB, const float* __restrict__ dwW,
    const float* __restrict__ dwB, const float* __restrict__ dlW,
    const float* __restrict__ dlB, float* __restrict__ out) {
  __shared__ float s[128];
  __shared__ float pg[20];
  __shared__ float nrm[2];
  __shared__ float cb[20];
  int t = threadIdx.x;
  int b = blockIdx.x >> 2;  // 4 blocks per batch
  if (t < 128) {
    float a = 0.f;
#pragma unroll
    for (int c = 0; c < 32; ++c) a += bsum[(size_t)(b * 32 + c) * 128 + t];
    s[t] = a;
  }
  __syncthreads();
  if (t < 20) {
    const float* W = t < 8 ? dsW + t * 128
                           : (t < 16 ? dwW + (t - 8) * 128 : dlW + (t - 16) * 128);
    float bias = t < 8 ? dsB[t] : (t < 16 ? dwB[t - 8] : dlB[t - 16]);
    float d = 0.f;
    for (int j = 0; j < 128; ++j) d += s[j] * W[j];
    float lf = (float)length[b];
    float pooled = (d + lf * bias) / (lf + 1e-8f);
    pg[t] = 1.f / (1.f + expf(-pooled));
  }
  __syncthreads();
  if (t == 0) {
    float a1 = 0.f, a2 = 0.f;
    for (int i = 0; i < 8; ++i) a1 += pg[i];
    for (int i = 8; i < 16; ++i) a2 += pg[i];
    nrm[0] = a1 + 1e-8f;
    nrm[1] = a2 + 1e-8f;
  }
  __syncthreads();
  if (t < 8) cb[t] = pg[t] / nrm[0];
  else if (t < 16) cb[t] = pg[t] / nrm[1];
  else if (t < 20) cb[t] = pg[t] * 2.0f;
  __syncthreads();

  int bn = blockIdx.x * 256 + t;
  float e = eva[bn];
  float y = e - 1.0f;
  float te = 1.0f, to = y;
  float cs = cb[0] * 0.5f * (1.0f - to);
#pragma unroll
  for (int i = 1; i < 8; ++i) {
    te = 2.f * y * to - te;
    to = 2.f * y * te - to;
    cs += cb[i] * 0.5f * (1.0f - to);
  }
  float cw[4];
#pragma unroll
  for (int j = 0; j < 4; ++j) {
    float fs = e * cb[16 + j];
    fs = (fs > 2.0f) ? 0.0f : fs;
    float yw = fs - 1.0f;
    float te2 = 1.0f, to2 = yw;
    float acc = 0.0f;
#pragma unroll
    for (int i = 1; i < 8; ++i) {
      te2 = 2.f * yw * to2 - te2;
      to2 = 2.f * yw * te2 - to2;
      acc += cb[8 + i] * 0.5f * (1.0f - te2);
    }
    cw[j] = acc;
  }
  float nr = cs * cs + cw[0] * cw[0] + cw[1] * cw[1] + cw[2] * cw[2] +
             cw[3] * cw[3];
  float inv = 1.0f / (sqrtf(nr) + 1e-8f);
  float* o = out + bn * 5;
  o[0] = cs * inv;
  o[1] = cw[0] * inv;
  o[2] = cw[1] * inv;
  o[3] = cw[2] * inv;
  o[4] = cw[3] * inv;
}

extern "C" void kernel_launch(void* const* d_in, const int* in_sizes, int n_in,
                              void* d_out, int out_size, void* d_ws,
                              size_t ws_size, hipStream_t stream) {
  const float* eva = (const float*)d_in[1];
  const int* length = (const int*)d_in[2];
  const float* eig_w_W = (const float*)d_in[3];
  const float* eig_w_b = (const float*)d_in[4];
  const float* ln1_s = (const float*)d_in[5];
  const float* ln1_b = (const float*)d_in[6];
  const float* ln2_s = (const float*)d_in[7];
  const float* ln2_b = (const float*)d_in[8];
  const float* qkv_W = (const float*)d_in[9];
  const float* qkv_b = (const float*)d_in[10];
  const float* out_W = (const float*)d_in[11];
  const float* out_b = (const float*)d_in[12];
  const float* ffn_W1 = (const float*)d_in[13];
  const float* ffn_b1 = (const float*)d_in[14];
  const float* ffn_W2 = (const float*)d_in[15];
  const float* ffn_b2 = (const float*)d_in[16];
  const float* dec_sca_W = (const float*)d_in[17];
  const float* dec_sca_b = (const float*)d_in[18];
  const float* dec_wav_W = (const float*)d_in[19];
  const float* dec_wav_b = (const float*)d_in[20];
  const float* dec_scl_W = (const float*)d_in[21];
  const float* dec_scl_b = (const float*)d_in[22];

  float* ws = (float*)d_ws;
  const size_t SZ = (size_t)NB * NN * ND;  // 2097152
  float* eig = ws;                         // f32 [16384][128]
  ushort* qg = (ushort*)(ws + SZ);         // bf16 [b,h,n,16] (scaled)
  ushort* kg = qg + SZ;                    // bf16 [b,h,n,16]
  ushort* vt = kg + SZ;                    // bf16 [b,h,d,n]
  ushort* attg = vt + SZ;                  // bf16 [16384][128]
  float* bsum = (float*)(attg + SZ);       // f32 [512][128]
  ushort* wbf = (ushort*)(bsum + 512 * 128);  // bf16 weights
  ushort* eWbf = wbf;
  ushort* qkvbf = wbf + 18432;
  ushort* outbf = wbf + 67584;
  ushort* w1bf = wbf + 83968;
  ushort* w2bf = wbf + 100352;

  kW<<<(116736 + 255) / 256, 256, 0, stream>>>(eig_w_W, qkv_W, out_W, ffn_W1,
                                               ffn_W2, wbf);
  kA<<<NB * NN / 32, 256, 0, stream>>>(eva, eWbf, eig_w_b, ln1_s, ln1_b, qkvbf,
                                       qkv_b, eig, qg, kg, vt);
  k_attn<<<NB * NH * 8, 512, 0, stream>>>(qg, kg, vt, length, attg);
  kB<<<NB * NN / 32, 256, 0, stream>>>(attg, outbf, out_b, ln2_s, ln2_b, w1bf,
                                       ffn_b1, w2bf, ffn_b2, eig, length, bsum);
  k_wave<<<(NB * NN) / 256, 256, 0, stream>>>(eva, bsum, length, dec_sca_W,
                                              dec_sca_b, dec_wav_W, dec_wav_b,
                                              dec_scl_W, dec_scl_b,
                                              (float*)d_out);
}